// Round 20
// baseline (818.141 us; speedup 1.0000x reference)
//
#include <hip/hip_runtime.h>
#include <math.h>
#include <stdint.h>

#define B 1024
#define H 512
#define E 256
#define L 128
#define LE (L*E)   // 32768

typedef _Float16 f16;
typedef _Float16 f16x8 __attribute__((ext_vector_type(8)));
typedef float f32x4 __attribute__((ext_vector_type(4)));
typedef const __attribute__((address_space(1))) uint32_t gu32;
typedef __attribute__((address_space(3))) uint32_t lu32;

// ---------------------------------------------------------------------------
// Persistent state in module device globals. Everything rewritten every call.
// X/H images in FRAGMENT ORDER (r17); W' gate-planar XOR layout (r18);
// B kt0..5 register-scheduled (r19). r20: PER-WAVE flags -> zero block-wide
// sync in the step loop (pure wave-level dataflow).
// ---------------------------------------------------------------------------
__device__ __align__(16) f16 g_Xs[128*16*4*4096];   // X images [t:128 pad][mt16][kt:4]
__device__ __align__(16) f16 g_Hh[128*16*8*4096];   // h(t) images, t=0..127 (134 MB)
__device__ __align__(16) f16 g_Ws[16*12*8192];      // gates W' [itile:16][kt:12] 128x64
__device__ __align__(16) f16 g_W1s[8*8192];         // W1' [kt:8] 128x64 (XOR layout)
__device__ __align__(16) f16 g_W2s[2*8192];         // W2' [kt:2]
__device__ __align__(16) f16 g_W3s[4*8192];         // W3' [nh:2][kt:2]
__device__ __align__(16) float g_bsum[2048];        // b_ih+b_hh, NATURAL order g*512+j

// r20: per-(block,wave) flags: g_flags[grp][nt*4+wv]. Relaxed agent atomics,
// same r15-validated same-XCD-L2 ordering argument (vmcnt(0) before store).
struct __align__(128) Flag { unsigned int v; unsigned int pad[31]; };
__device__ Flag g_flags[8][128];
__device__ unsigned int g_slot[8];

__device__ __forceinline__ float fsigm(float x) {
    return __builtin_amdgcn_rcpf(1.0f + __expf(-x));
}
__device__ __forceinline__ float ftanh(float x) {
    return 2.0f * __builtin_amdgcn_rcpf(1.0f + __expf(-2.0f * x)) - 1.0f;
}

// ---------------------------------------------------------------------------
// conv_w: gates W' images, GATE-PLANAR rows (r18) + bias sums natural order
// ---------------------------------------------------------------------------
__global__ __launch_bounds__(256) void conv_w(
    const float* __restrict__ W_ih, const float* __restrict__ W_hh,
    const float* __restrict__ b_ih, const float* __restrict__ b_hh)
{
    int gid = blockIdx.x*256 + threadIdx.x;   // 196608
    int kb  = gid & 7;
    int r1  = gid >> 3;
    int row = r1 & 127;
    int r2  = r1 >> 7;
    int kt  = r2 % 12;
    int nt  = r2 / 12;
    int ntblock = nt*2 + (row >> 6);
    int c = row & 63;
    int wrow = (c >> 4)*512 + ntblock*16 + (c & 15);
    int k = kt*64 + kb*8;
    const float* src = (k < 256) ? (W_ih + wrow*256 + k)
                                 : (W_hh + wrow*512 + (k - 256));
    f16x8 v;
    #pragma unroll
    for (int e = 0; e < 8; ++e) v[e] = (f16)src[e];
    char* dst = (char*)g_Ws + (size_t)(nt*12 + kt)*16384
              + row*128 + ((kb*16) ^ ((row & 7) << 4));
    *(f16x8*)dst = v;
    if (gid < 2048) g_bsum[gid] = b_ih[gid] + b_hh[gid];
}

// ---------------------------------------------------------------------------
// conv_mlp: W1/W2/W3 fp16 tile images (XOR layout, unchanged)
// ---------------------------------------------------------------------------
__global__ __launch_bounds__(256) void conv_mlp(
    const float* __restrict__ W1, const float* __restrict__ W2,
    const float* __restrict__ W3)
{
    int gid = blockIdx.x*256 + threadIdx.x;   // 14336
    if (gid < 8192) {                         // W1 (128,512) -> 8 tiles
        int s = gid;
        int kb = s & 7, row = (s >> 3) & 127, kt = s >> 10;
        const float* src = W1 + row*512 + kt*64 + kb*8;
        f16x8 v;
        #pragma unroll
        for (int e = 0; e < 8; ++e) v[e] = (f16)src[e];
        char* dst = (char*)g_W1s + (size_t)kt*16384
                  + row*128 + ((kb*16) ^ ((row & 7) << 4));
        *(f16x8*)dst = v;
    } else if (gid < 10240) {                 // W2 (128,128) -> 2 tiles
        int s = gid - 8192;
        int kb = s & 7, row = (s >> 3) & 127, kt = s >> 10;
        const float* src = W2 + row*128 + kt*64 + kb*8;
        f16x8 v;
        #pragma unroll
        for (int e = 0; e < 8; ++e) v[e] = (f16)src[e];
        char* dst = (char*)g_W2s + (size_t)kt*16384
                  + row*128 + ((kb*16) ^ ((row & 7) << 4));
        *(f16x8*)dst = v;
    } else if (gid < 14336) {                 // W3 (256,128) -> [nh:2][kt:2]
        int s = gid - 10240;
        int kb = s & 7, r256 = (s >> 3) & 255, kt = s >> 11;
        int nh = r256 >> 7, row = r256 & 127;
        const float* src = W3 + r256*128 + kt*64 + kb*8;
        f16x8 v;
        #pragma unroll
        for (int e = 0; e < 8; ++e) v[e] = (f16)src[e];
        char* dst = (char*)g_W3s + (size_t)(nh*2 + kt)*16384
                  + row*128 + ((kb*16) ^ ((row & 7) << 4));
        *(f16x8*)dst = v;
    }
}

// ---------------------------------------------------------------------------
// conv_x: X fp16 images in FRAGMENT ORDER (unchanged from r17)
// ---------------------------------------------------------------------------
__global__ __launch_bounds__(256) void conv_x(const float* __restrict__ padded)
{
    int gid = blockIdx.x*256 + threadIdx.x;   // 127*1024*32 = 4161536 exact
    int kq = gid & 31;
    int b  = (gid >> 5) & 1023;
    int t  = gid >> 15;
    const float* src = padded + (size_t)b*LE + t*E + kq*8;
    float4 v0 = *(const float4*)src;
    float4 v1 = *(const float4*)(src + 4);
    f16x8 v;
    v[0]=(f16)v0.x; v[1]=(f16)v0.y; v[2]=(f16)v0.z; v[3]=(f16)v0.w;
    v[4]=(f16)v1.x; v[5]=(f16)v1.y; v[6]=(f16)v1.z; v[7]=(f16)v1.w;
    int ktimg = kq >> 3;
    int kin0  = (kq & 7) * 8;
    int kgrp  = kin0 >> 5;
    int chunk = (kin0 & 31) >> 3;
    int row = b & 63, mt16 = b >> 6;
    int rowgrp = row >> 4;
    int lane = (row & 15) | (chunk << 4);
    char* dst = (char*)g_Xs + (size_t)((t*16 + mt16)*4 + ktimg)*8192
              + (rowgrp*2 + kgrp)*1024 + lane*16;
    *(f16x8*)dst = v;
}

// ---------------------------------------------------------------------------
// init: g_Hh[0] <- hidden (fragment order), out row 0 <- one-hot, flags reset
// ---------------------------------------------------------------------------
__global__ __launch_bounds__(256) void init_kernel(
    const float* __restrict__ hidden, float* __restrict__ out)
{
    int i = blockIdx.x * 256 + threadIdx.x;
    if (i < 1024) g_flags[i >> 7][i & 127].v = 0u;
    if (i < 8) g_slot[i] = 0u;
    if (i < B*H) {
        float hv = hidden[i];
        int b = i >> 9, j = i & 511;
        int mt = b >> 6, row = b & 63, ktimg = j >> 6, kin = j & 63;
        int rowgrp = row >> 4, kgrp = kin >> 5;
        int lane = (row & 15) | (((kin & 31) >> 3) << 4);
        int elem = kin & 7;
        char* dst = (char*)g_Hh + (size_t)(mt*8 + ktimg)*8192
                  + (rowgrp*2 + kgrp)*1024 + lane*16 + elem*2;
        *(f16*)dst = (f16)hv;
    }
    if (i < B*E) {
        int b = i >> 8, e = i & 255;
        out[b*LE + e] = (e == 0) ? 1.0f : 0.0f;
    }
}

// ---------------------------------------------------------------------------
// step_all: r19 structure + r20 per-wave flags. 8 groups (= physical XCDs)
// x 32 blocks, 256 threads. ZERO block-wide sync in the step loop: each wave
// releases its own flag after ITS h store drains; waiters poll all 128
// wave-flags (2 relaxed loads/lane + __all).
// ---------------------------------------------------------------------------
__global__ __launch_bounds__(256, 1) void step_all()
{
    __shared__ __align__(16) char lds[102400];   // 96K B + 4 x 1K wave Hs
    char* Bb = lds;

    const int tid  = threadIdx.x;
    const int lane = tid & 63;
    const int wv   = tid >> 6;          // 0..3
    const int l15  = lane & 15;
    const int quad = lane >> 4;
    const int klo  = quad << 4;
    f16* HsW = (f16*)(lds + 98304 + wv*1024);    // wave-private [32][16]

    // runtime grouping: grp = physical XCD, nt = slot within XCD.
    if (tid == 0) {
        uint32_t xcc;
        asm volatile("s_getreg_b32 %0, hwreg(HW_REG_XCC_ID)" : "=s"(xcc));
        xcc &= 7u;
        unsigned int slot = atomicAdd(&g_slot[xcc], 1u);
        ((int*)lds)[0] = (int)xcc;
        ((int*)lds)[1] = (int)(slot & 31u);
    }
    __syncthreads();
    const int grp = ((volatile int*)lds)[0];
    const int nt  = ((volatile int*)lds)[1];
    __syncthreads();   // reads done before B staging overwrites lds[0..7]

    // ---- persistent B load (once): rows (nt&1)*64..+64 of itile nt>>1 ----
    {
        const char* src = (const char*)g_Ws + (size_t)(nt >> 1)*12*16384
                        + (size_t)(nt & 1)*64*128;
        #pragma unroll
        for (int it = 0; it < 24; ++it) {
            int c = wv*24 + it;             // 0..95 chunks of 1KB
            int kt = c >> 3, cc = c & 7;
            __builtin_amdgcn_global_load_lds(
                (gu32*)(src + (size_t)kt*16384 + cc*1024 + lane*16),
                (lu32*)(Bb + c*1024 + lane*16), 16, 0, 0);
        }
    }
    // per-lane bias: gate g at col j = nt*16 + l15
    float bsv[4];
    #pragma unroll
    for (int g = 0; g < 4; ++g) bsv[g] = g_bsum[g*512 + nt*16 + l15];

    float creg[2][4];
    #pragma unroll
    for (int m = 0; m < 2; ++m)
        #pragma unroll
        for (int i = 0; i < 4; ++i) creg[m][i] = 0.0f;

    asm volatile("s_waitcnt vmcnt(0)" ::: "memory");
    __syncthreads();   // B resident for all waves

    // ---- r19: kt0..5 of B -> registers (compiler-scheduled) ----
    f16x8 bw[6][2][4];
    #pragma unroll
    for (int kt = 0; kt < 6; ++kt)
        #pragma unroll
        for (int kkl = 0; kkl < 2; ++kkl) {
            const int kb = kkl*64 + klo;
            #pragma unroll
            for (int n = 0; n < 4; ++n) {
                int r = n*16 + l15;
                bw[kt][kkl][n] = *(const f16x8*)(Bb + kt*8192 + r*128
                                                 + (kb ^ ((r & 7) << 4)));
            }
        }

    const int sub = wv >> 1;            // which 64-row image
    const int rg2 = (wv & 1) * 2;       // rowgrp base within image

    f16x8 az[3][4];
    auto loada = [&](int t_, int kt_, int s_) {
        const char* img = (kt_ < 4)
            ? (const char*)g_Xs + (size_t)((t_*16 + grp*2 + sub)*4 + kt_)*8192
            : (const char*)g_Hh + (size_t)((t_*16 + grp*2 + sub)*8 + (kt_-4))*8192;
        const char* fb = img + (size_t)(rg2*2)*1024 + lane*16;
        az[s_][0] = *(const f16x8*)(fb);
        az[s_][1] = *(const f16x8*)(fb + 1024);
        az[s_][2] = *(const f16x8*)(fb + 2048);
        az[s_][3] = *(const f16x8*)(fb + 3072);
    };

    // r20: poll ALL 128 wave-flags (2 per lane)
    auto wave_wait = [&](unsigned int target) {
        for (;;) {
            unsigned int v0 = __hip_atomic_load(&g_flags[grp][lane].v,
                                __ATOMIC_RELAXED, __HIP_MEMORY_SCOPE_AGENT);
            unsigned int v1 = __hip_atomic_load(&g_flags[grp][64 + lane].v,
                                __ATOMIC_RELAXED, __HIP_MEMORY_SCOPE_AGENT);
            if (__all(v0 >= target && v1 >= target)) break;
            __builtin_amdgcn_s_sleep(1);
        }
        asm volatile("" ::: "memory");
    };

    // prologue: X(0) kt0..2
    loada(0, 0, 0); loada(0, 1, 1); loada(0, 2, 2);

    #pragma unroll 1
    for (int t = 0; t < 127; ++t) {
        f32x4 acc[2][4];
        #pragma unroll
        for (int m = 0; m < 2; ++m)
            #pragma unroll
            for (int n = 0; n < 4; ++n) acc[m][n] = (f32x4){0.f,0.f,0.f,0.f};

        #pragma unroll
        for (int kt = 0; kt < 12; ++kt) {
            const int s = kt % 3;
            #pragma unroll
            for (int kkl = 0; kkl < 2; ++kkl) {
                f16x8 b[4];
                if (kt < 6) {
                    #pragma unroll
                    for (int n = 0; n < 4; ++n) b[n] = bw[kt][kkl][n];
                } else {
                    const char* Br = Bb + kt*8192;
                    const int kb = kkl*64 + klo;
                    #pragma unroll
                    for (int n = 0; n < 4; ++n) {
                        int r = n*16 + l15;
                        b[n] = *(const f16x8*)(Br + r*128 + (kb ^ ((r & 7) << 4)));
                    }
                }
                #pragma unroll
                for (int n = 0; n < 4; ++n) {
                    acc[0][n] = __builtin_amdgcn_mfma_f32_16x16x32_f16(
                        az[s][0 + kkl], b[n], acc[0][n], 0, 0, 0);
                    acc[1][n] = __builtin_amdgcn_mfma_f32_16x16x32_f16(
                        az[s][2 + kkl], b[n], acc[1][n], 0, 0, 0);
                }
            }
            if (kt == 1) wave_wait((unsigned)t);   // h(t) visible before kt4 issue
            if (kt < 9) loada(t, kt + 3, s);
            else        loada(t + 1, kt - 9, s);   // X(t+1); g_Xs padded
        }

        // ---- shuffle-free epilogue: all 4 gates in-lane per cell ----
        #pragma unroll
        for (int m = 0; m < 2; ++m)
            #pragma unroll
            for (int i = 0; i < 4; ++i) {
                float iv = fsigm(acc[m][0][i] + bsv[0]);
                float fv = fsigm(acc[m][1][i] + bsv[1]);
                float gg = ftanh(acc[m][2][i] + bsv[2]);
                float ov = fsigm(acc[m][3][i] + bsv[3]);
                float cv = fv * creg[m][i] + iv * gg;
                creg[m][i] = cv;
                float hv = ov * ftanh(cv);
                int rowl = m*16 + quad*4 + i;       // 0..31 wave-local
                HsW[rowl*16 + l15] = (f16)hv;       // col = l15
            }
        asm volatile("s_waitcnt lgkmcnt(0)" ::: "memory");  // wave's Hs done
        // wave-private coalesced h store in FRAGMENT ORDER (unchanged r17)
        {
            int rg = lane >> 5, lo = lane & 31;
            int ktimg = nt >> 2;
            int kgrp  = (nt & 3) >> 1;
            int c0    = (nt & 1) * 2;
            char* img = (char*)g_Hh
                + (size_t)(((t + 1)*16 + grp*2 + sub)*8 + ktimg)*8192;
            int frag = (rg2 + rg)*2 + kgrp;
            f16x8 hv8 = *(const f16x8*)(HsW + (rg*16 + (lo & 15))*16 + (lo >> 4)*8);
            *(f16x8*)(img + frag*1024 + (size_t)(c0*16 + lo)*16) = hv8;
        }
        asm volatile("s_waitcnt vmcnt(0)" ::: "memory");  // THIS wave's h in L2
        if (lane == 0)   // per-wave release: zero block-wide sync
            __hip_atomic_store(&g_flags[grp][nt*4 + wv].v, (unsigned)(t + 1),
                               __ATOMIC_RELAXED, __HIP_MEMORY_SCOPE_AGENT);
    }
}

// ---------------------------------------------------------------------------
// mlp_all: batched 3-layer MLP for ALL tokens (r17 structure, unchanged)
// ---------------------------------------------------------------------------
__global__ __launch_bounds__(256) void mlp_all(
    const float* __restrict__ b1, const float* __restrict__ b2,
    const float* __restrict__ b3, float* __restrict__ out)
{
    __shared__ char lds[65536];
    char* Wb = lds;            // 2 x 16384
    char* Ab = lds + 32768;    // 2 x 8192 (later Z2)
    char* Z1 = lds + 49152;    // 16384
    const int tid  = threadIdx.x;
    const int lane = tid & 63;
    const int w    = tid >> 6;
    const int bi   = blockIdx.x;
    const int tok  = 1 + (bi >> 4);
    const int mt   = bi & 15;
    const char* gH = (const char*)g_Hh + (size_t)(tok*16 + mt)*8*8192;
    float* outb = out + (size_t)(mt*64)*LE + (size_t)tok*E;

    float b1v[2], b2v[2], b3v[2][2];
    #pragma unroll
    for (int n = 0; n < 2; ++n) {
        int col = w*32 + n*16 + (lane & 15);
        b1v[n] = b1[col]; b2v[n] = b2[col];
        b3v[0][n] = b3[col]; b3v[1][n] = b3[128 + col];
    }
    const int kb0_0 = ((lane >> 4) << 4);

    f32x4 acc[4][2];
    #pragma unroll
    for (int m = 0; m < 4; ++m) { acc[m][0] = (f32x4){0,0,0,0}; acc[m][1] = (f32x4){0,0,0,0}; }

    #pragma unroll
    for (int it = 0; it < 2; ++it) {
        int c = w*2 + it;
        __builtin_amdgcn_global_load_lds((gu32*)(gH + c*1024 + lane*16),
                                         (lu32*)(Ab + c*1024 + lane*16), 16, 0, 0);
    }
    #pragma unroll
    for (int it = 0; it < 4; ++it) {
        int c = w*4 + it;
        __builtin_amdgcn_global_load_lds((gu32*)((const char*)g_W1s + c*1024 + lane*16),
                                         (lu32*)(Wb + c*1024 + lane*16), 16, 0, 0);
    }
    __syncthreads();

    for (int kt = 0; kt < 8; ++kt) {
        const int cur = kt & 1;
        if (kt < 7) {
            const char* gA = gH + (size_t)(kt+1)*8192;
            const char* gW = (const char*)g_W1s + (size_t)(kt+1)*16384;
            char* dA = Ab + (cur^1)*8192;
            char* dW = Wb + (cur^1)*16384;
            #pragma unroll
            for (int it = 0; it < 2; ++it) {
                int c = w*2 + it;
                __builtin_amdgcn_global_load_lds((gu32*)(gA + c*1024 + lane*16),
                                                 (lu32*)(dA + c*1024 + lane*16), 16, 0, 0);
            }
            #pragma unroll
            for (int it = 0; it < 4; ++it) {
                int c = w*4 + it;
                __builtin_amdgcn_global_load_lds((gu32*)(gW + c*1024 + lane*16),
                                                 (lu32*)(dW + c*1024 + lane*16), 16, 0, 0);
            }
        }
        const char* Ar = Ab + cur*8192;
        const char* Br = Wb + cur*16384;
        #pragma unroll
        for (int kk = 0; kk < 2; ++kk) {
            const int kb0 = kk*64 + kb0_0;
            f16x8 a[4], b[2];
            #pragma unroll
            for (int m = 0; m < 4; ++m)
                a[m] = *(const f16x8*)(Ar + (size_t)(m*2 + kk)*1024 + lane*16);
            #pragma unroll
            for (int n = 0; n < 2; ++n) {
                int br = w*32 + n*16 + (lane & 15);
                b[n] = *(const f16x8*)(Br + br*128 + (kb0 ^ ((br & 7) << 4)));
            }
            #pragma unroll
            for (int m = 0; m < 4; ++m)
                #pragma unroll
                for (int n = 0; n < 2; ++n)
                    acc[m][n] = __builtin_amdgcn_mfma_f32_16x16x32_f16(a[m], b[n], acc[m][n], 0, 0, 0);
        }
        __syncthreads();
    }

    #pragma unroll
    for (int m = 0; m < 4; ++m)
        #pragma unroll
        for (int n = 0; n < 2; ++n)
            #pragma unroll
            for (int i = 0; i < 4; ++i) {
                int row = m*16 + ((lane >> 4) << 2) + i;
                int col = w*32 + n*16 + (lane & 15);
                float v = fmaxf(acc[m][n][i] + b1v[n], 0.0f);
                *(f16*)(Z1 + (col >> 6)*8192 + row*128
                        + (((col & 63)*2) ^ ((row & 7) << 4))) = (f16)v;
            }
    __syncthreads();

    #pragma unroll
    for (int it = 0; it < 8; ++it) {
        int c = w*8 + it;
        __builtin_amdgcn_global_load_lds((gu32*)((const char*)g_W2s + c*1024 + lane*16),
                                         (lu32*)(Wb + c*1024 + lane*16), 16, 0, 0);
    }
    __syncthreads();
    #pragma unroll
    for (int m = 0; m < 4; ++m) { acc[m][0] = (f32x4){0,0,0,0}; acc[m][1] = (f32x4){0,0,0,0}; }
    #pragma unroll
    for (int kt = 0; kt < 2; ++kt)
        #pragma unroll
        for (int kk = 0; kk < 2; ++kk) {
            const int kb0 = kk*64 + kb0_0;
            f16x8 a[4], b[2];
            #pragma unroll
            for (int m = 0; m < 4; ++m) {
                int ar = m*16 + (lane & 15);
                a[m] = *(const f16x8*)(Z1 + kt*8192 + ar*128 + (kb0 ^ ((ar & 7) << 4)));
            }
            #pragma unroll
            for (int n = 0; n < 2; ++n) {
                int br = w*32 + n*16 + (lane & 15);
                b[n] = *(const f16x8*)(Wb + kt*16384 + br*128 + (kb0 ^ ((br & 7) << 4)));
            }
            #pragma unroll
            for (int m = 0; m < 4; ++m)
                #pragma unroll
                for (int n = 0; n < 2; ++n)
                    acc[m][n] = __builtin_amdgcn_mfma_f32_16x16x32_f16(a[m], b[n], acc[m][n], 0, 0, 0);
        }
    __syncthreads();

    #pragma unroll
    for (int m = 0; m < 4; ++m)
        #pragma unroll
        for (int n = 0; n < 2; ++n)
            #pragma unroll
            for (int i = 0; i < 4; ++i) {
                int row = m*16 + ((lane >> 4) << 2) + i;
                int col = w*32 + n*16 + (lane & 15);
                float v = fmaxf(acc[m][n][i] + b2v[n], 0.0f);
                *(f16*)(Ab + (col >> 6)*8192 + row*128
                        + (((col & 63)*2) ^ ((row & 7) << 4))) = (f16)v;
            }
    __syncthreads();

    #pragma unroll
    for (int nh = 0; nh < 2; ++nh) {
        #pragma unroll
        for (int it = 0; it < 8; ++it) {
            int c = w*8 + it;
            __builtin_amdgcn_global_load_lds(
                (gu32*)((const char*)g_W3s + (size_t)nh*32768 + c*1024 + lane*16),
                (lu32*)(Wb + c*1024 + lane*16), 16, 0, 0);
        }
        __syncthreads();
        #pragma unroll
        for (int m = 0; m < 4; ++m) { acc[m][0] = (f32x4){0,0,0,0}; acc[m][1] = (f32x4){0,0,0,0}; }
        #pragma unroll
        for (int kt = 0; kt < 2; ++kt)
            #pragma unroll
            for (int kk = 0; kk < 2; ++kk) {
                const int kb0 = kk*64 + kb0_0;
                f16x8 a[4], b[2];
                #pragma unroll
                for (int m = 0; m < 4; ++m) {
                    int ar = m*16 + (lane & 15);
                    a[m] = *(const f16x8*)(Ab + kt*8192 + ar*128 + (kb0 ^ ((ar & 7) << 4)));
                }
                #pragma unroll
                for (int n = 0; n < 2; ++n) {
                    int br = w*32 + n*16 + (lane & 15);
                    b[n] = *(const f16x8*)(Wb + kt*16384 + br*128 + (kb0 ^ ((br & 7) << 4)));
                }
                #pragma unroll
                for (int m = 0; m < 4; ++m)
                    #pragma unroll
                    for (int n = 0; n < 2; ++n)
                        acc[m][n] = __builtin_amdgcn_mfma_f32_16x16x32_f16(a[m], b[n], acc[m][n], 0, 0, 0);
            }
        #pragma unroll
        for (int m = 0; m < 4; ++m)
            #pragma unroll
            for (int n = 0; n < 2; ++n)
                #pragma unroll
                for (int i = 0; i < 4; ++i) {
                    int row = m*16 + ((lane >> 4) << 2) + i;
                    int col = nh*128 + w*32 + n*16 + (lane & 15);
                    outb[(size_t)row*LE + col] = acc[m][n][i] + b3v[nh][n];
                }
        __syncthreads();
    }
}

// ---------------------------------------------------------------------------
extern "C" void kernel_launch(void* const* d_in, const int* in_sizes, int n_in,
                              void* d_out, int out_size, void* d_ws, size_t ws_size,
                              hipStream_t stream) {
    (void)in_sizes; (void)n_in; (void)out_size; (void)d_ws; (void)ws_size;
    const float* hidden = (const float*)d_in[0];
    const float* padded = (const float*)d_in[1];
    const float* W_ih   = (const float*)d_in[2];
    const float* W_hh   = (const float*)d_in[3];
    const float* b_ih   = (const float*)d_in[4];
    const float* b_hh   = (const float*)d_in[5];
    const float* W1     = (const float*)d_in[6];
    const float* b1     = (const float*)d_in[7];
    const float* W2     = (const float*)d_in[8];
    const float* b2     = (const float*)d_in[9];
    const float* W3     = (const float*)d_in[10];
    const float* b3     = (const float*)d_in[11];
    float* out = (float*)d_out;

    conv_w<<<768, 256, 0, stream>>>(W_ih, W_hh, b_ih, b_hh);
    conv_mlp<<<56, 256, 0, stream>>>(W1, W2, W3);
    conv_x<<<16256, 256, 0, stream>>>(padded);
    init_kernel<<<2048, 256, 0, stream>>>(hidden, out);
    step_all<<<256, 256, 0, stream>>>();
    mlp_all<<<2032, 256, 0, stream>>>(b1, b2, b3, out);
}

// Round 21
// 653.275 us; speedup vs baseline: 1.2524x; 1.2524x over previous
//
#include <hip/hip_runtime.h>
#include <math.h>
#include <stdint.h>

#define B 1024
#define H 512
#define E 256
#define L 128
#define LE (L*E)   // 32768

typedef _Float16 f16;
typedef _Float16 f16x8 __attribute__((ext_vector_type(8)));
typedef float f32x4 __attribute__((ext_vector_type(4)));
typedef const __attribute__((address_space(1))) uint32_t gu32;
typedef __attribute__((address_space(3))) uint32_t lu32;

// ---------------------------------------------------------------------------
// Persistent state in module device globals. Everything rewritten every call.
// X/H images in FRAGMENT ORDER (r17): 64x64 image = 8 frags of 1 KB;
// frag = 16 rows x 32 k; addr = img + frag*1024 + lane*16.
// W' images: XOR layout, rows GATE-PLANAR per 64-col block (r18).
// r19: B kt0..5 register-scheduled per wave. r20's per-wave flags REVERTED
// (quadrupled flag traffic, de-correlated wave A-streams: 575->697us).
// ---------------------------------------------------------------------------
__device__ __align__(16) f16 g_Xs[128*16*4*4096];   // X images [t:128 pad][mt16][kt:4]
__device__ __align__(16) f16 g_Hh[128*16*8*4096];   // h(t) images, t=0..127 (134 MB)
__device__ __align__(16) f16 g_Ws[16*12*8192];      // gates W' [itile:16][kt:12] 128x64
__device__ __align__(16) f16 g_W1s[8*8192];         // W1' [kt:8] 128x64 (XOR layout)
__device__ __align__(16) f16 g_W2s[2*8192];         // W2' [kt:2]
__device__ __align__(16) f16 g_W3s[4*8192];         // W3' [nh:2][kt:2]
__device__ __align__(16) float g_bsum[2048];        // b_ih+b_hh, NATURAL order g*512+j

// r15-validated sync: groups = PHYSICAL XCDs, relaxed flags, no wbl2/inv.
struct __align__(128) Flag { unsigned int v; unsigned int pad[31]; };
__device__ Flag g_flags[8][32];
__device__ unsigned int g_slot[8];

__device__ __forceinline__ float fsigm(float x) {
    return __builtin_amdgcn_rcpf(1.0f + __expf(-x));
}
__device__ __forceinline__ float ftanh(float x) {
    return 2.0f * __builtin_amdgcn_rcpf(1.0f + __expf(-2.0f * x)) - 1.0f;
}

// ---------------------------------------------------------------------------
// conv_w: gates W' images, GATE-PLANAR rows (r18) + bias sums natural order
// ---------------------------------------------------------------------------
__global__ __launch_bounds__(256) void conv_w(
    const float* __restrict__ W_ih, const float* __restrict__ W_hh,
    const float* __restrict__ b_ih, const float* __restrict__ b_hh)
{
    int gid = blockIdx.x*256 + threadIdx.x;   // 196608
    int kb  = gid & 7;
    int r1  = gid >> 3;
    int row = r1 & 127;
    int r2  = r1 >> 7;
    int kt  = r2 % 12;
    int nt  = r2 / 12;
    int ntblock = nt*2 + (row >> 6);
    int c = row & 63;
    int wrow = (c >> 4)*512 + ntblock*16 + (c & 15);
    int k = kt*64 + kb*8;
    const float* src = (k < 256) ? (W_ih + wrow*256 + k)
                                 : (W_hh + wrow*512 + (k - 256));
    f16x8 v;
    #pragma unroll
    for (int e = 0; e < 8; ++e) v[e] = (f16)src[e];
    char* dst = (char*)g_Ws + (size_t)(nt*12 + kt)*16384
              + row*128 + ((kb*16) ^ ((row & 7) << 4));
    *(f16x8*)dst = v;
    if (gid < 2048) g_bsum[gid] = b_ih[gid] + b_hh[gid];
}

// ---------------------------------------------------------------------------
// conv_mlp: W1/W2/W3 fp16 tile images (XOR layout, unchanged)
// ---------------------------------------------------------------------------
__global__ __launch_bounds__(256) void conv_mlp(
    const float* __restrict__ W1, const float* __restrict__ W2,
    const float* __restrict__ W3)
{
    int gid = blockIdx.x*256 + threadIdx.x;   // 14336
    if (gid < 8192) {                         // W1 (128,512) -> 8 tiles
        int s = gid;
        int kb = s & 7, row = (s >> 3) & 127, kt = s >> 10;
        const float* src = W1 + row*512 + kt*64 + kb*8;
        f16x8 v;
        #pragma unroll
        for (int e = 0; e < 8; ++e) v[e] = (f16)src[e];
        char* dst = (char*)g_W1s + (size_t)kt*16384
                  + row*128 + ((kb*16) ^ ((row & 7) << 4));
        *(f16x8*)dst = v;
    } else if (gid < 10240) {                 // W2 (128,128) -> 2 tiles
        int s = gid - 8192;
        int kb = s & 7, row = (s >> 3) & 127, kt = s >> 10;
        const float* src = W2 + row*128 + kt*64 + kb*8;
        f16x8 v;
        #pragma unroll
        for (int e = 0; e < 8; ++e) v[e] = (f16)src[e];
        char* dst = (char*)g_W2s + (size_t)kt*16384
                  + row*128 + ((kb*16) ^ ((row & 7) << 4));
        *(f16x8*)dst = v;
    } else if (gid < 14336) {                 // W3 (256,128) -> [nh:2][kt:2]
        int s = gid - 10240;
        int kb = s & 7, r256 = (s >> 3) & 255, kt = s >> 11;
        int nh = r256 >> 7, row = r256 & 127;
        const float* src = W3 + r256*128 + kt*64 + kb*8;
        f16x8 v;
        #pragma unroll
        for (int e = 0; e < 8; ++e) v[e] = (f16)src[e];
        char* dst = (char*)g_W3s + (size_t)(nh*2 + kt)*16384
                  + row*128 + ((kb*16) ^ ((row & 7) << 4));
        *(f16x8*)dst = v;
    }
}

// ---------------------------------------------------------------------------
// conv_x: X fp16 images in FRAGMENT ORDER (unchanged from r17)
// ---------------------------------------------------------------------------
__global__ __launch_bounds__(256) void conv_x(const float* __restrict__ padded)
{
    int gid = blockIdx.x*256 + threadIdx.x;   // 127*1024*32 = 4161536 exact
    int kq = gid & 31;
    int b  = (gid >> 5) & 1023;
    int t  = gid >> 15;
    const float* src = padded + (size_t)b*LE + t*E + kq*8;
    float4 v0 = *(const float4*)src;
    float4 v1 = *(const float4*)(src + 4);
    f16x8 v;
    v[0]=(f16)v0.x; v[1]=(f16)v0.y; v[2]=(f16)v0.z; v[3]=(f16)v0.w;
    v[4]=(f16)v1.x; v[5]=(f16)v1.y; v[6]=(f16)v1.z; v[7]=(f16)v1.w;
    int ktimg = kq >> 3;
    int kin0  = (kq & 7) * 8;
    int kgrp  = kin0 >> 5;
    int chunk = (kin0 & 31) >> 3;
    int row = b & 63, mt16 = b >> 6;
    int rowgrp = row >> 4;
    int lane = (row & 15) | (chunk << 4);
    char* dst = (char*)g_Xs + (size_t)((t*16 + mt16)*4 + ktimg)*8192
              + (rowgrp*2 + kgrp)*1024 + lane*16;
    *(f16x8*)dst = v;
}

// ---------------------------------------------------------------------------
// init: g_Hh[0] <- hidden (fragment order), out row 0 <- one-hot, flags reset
// ---------------------------------------------------------------------------
__global__ __launch_bounds__(256) void init_kernel(
    const float* __restrict__ hidden, float* __restrict__ out)
{
    int i = blockIdx.x * 256 + threadIdx.x;
    if (i < 256) g_flags[i >> 5][i & 31].v = 0u;
    if (i < 8) g_slot[i] = 0u;
    if (i < B*H) {
        float hv = hidden[i];
        int b = i >> 9, j = i & 511;
        int mt = b >> 6, row = b & 63, ktimg = j >> 6, kin = j & 63;
        int rowgrp = row >> 4, kgrp = kin >> 5;
        int lane = (row & 15) | (((kin & 31) >> 3) << 4);
        int elem = kin & 7;
        char* dst = (char*)g_Hh + (size_t)(mt*8 + ktimg)*8192
                  + (rowgrp*2 + kgrp)*1024 + lane*16 + elem*2;
        *(f16*)dst = (f16)hv;
    }
    if (i < B*E) {
        int b = i >> 8, e = i & 255;
        out[b*LE + e] = (e == 0) ? 1.0f : 0.0f;
    }
}

// ---------------------------------------------------------------------------
// step_all: r19 winner. 8 groups (= physical XCDs) x 32 blocks, 256 threads.
// B kt0..5 register-scheduled, kt6..11 from persistent LDS; A frags
// coalesced global->reg; zero s_barriers in the kt loop; shuffle-free
// gate-planar epilogue; one block flag + one __syncthreads per step.
// ---------------------------------------------------------------------------
__global__ __launch_bounds__(256, 1) void step_all()
{
    __shared__ __align__(16) char lds[102400];   // 96K B + 4 x 1K wave Hs
    char* Bb = lds;

    const int tid  = threadIdx.x;
    const int lane = tid & 63;
    const int wv   = tid >> 6;          // 0..3
    const int l15  = lane & 15;
    const int quad = lane >> 4;
    const int klo  = quad << 4;
    f16* HsW = (f16*)(lds + 98304 + wv*1024);    // wave-private [32][16]

    // runtime grouping: grp = physical XCD, nt = slot within XCD.
    if (tid == 0) {
        uint32_t xcc;
        asm volatile("s_getreg_b32 %0, hwreg(HW_REG_XCC_ID)" : "=s"(xcc));
        xcc &= 7u;
        unsigned int slot = atomicAdd(&g_slot[xcc], 1u);
        ((int*)lds)[0] = (int)xcc;
        ((int*)lds)[1] = (int)(slot & 31u);
    }
    __syncthreads();
    const int grp = ((volatile int*)lds)[0];
    const int nt  = ((volatile int*)lds)[1];
    __syncthreads();   // reads done before B staging overwrites lds[0..7]

    // ---- persistent B load (once): rows (nt&1)*64..+64 of itile nt>>1 ----
    {
        const char* src = (const char*)g_Ws + (size_t)(nt >> 1)*12*16384
                        + (size_t)(nt & 1)*64*128;
        #pragma unroll
        for (int it = 0; it < 24; ++it) {
            int c = wv*24 + it;             // 0..95 chunks of 1KB
            int kt = c >> 3, cc = c & 7;
            __builtin_amdgcn_global_load_lds(
                (gu32*)(src + (size_t)kt*16384 + cc*1024 + lane*16),
                (lu32*)(Bb + c*1024 + lane*16), 16, 0, 0);
        }
    }
    // per-lane bias: gate g at col j = nt*16 + l15
    float bsv[4];
    #pragma unroll
    for (int g = 0; g < 4; ++g) bsv[g] = g_bsum[g*512 + nt*16 + l15];

    float creg[2][4];
    #pragma unroll
    for (int m = 0; m < 2; ++m)
        #pragma unroll
        for (int i = 0; i < 4; ++i) creg[m][i] = 0.0f;

    asm volatile("s_waitcnt vmcnt(0)" ::: "memory");
    __syncthreads();   // B resident for all waves

    // ---- r19: kt0..5 of B -> registers (compiler-scheduled) ----
    f16x8 bw[6][2][4];
    #pragma unroll
    for (int kt = 0; kt < 6; ++kt)
        #pragma unroll
        for (int kkl = 0; kkl < 2; ++kkl) {
            const int kb = kkl*64 + klo;
            #pragma unroll
            for (int n = 0; n < 4; ++n) {
                int r = n*16 + l15;
                bw[kt][kkl][n] = *(const f16x8*)(Bb + kt*8192 + r*128
                                                 + (kb ^ ((r & 7) << 4)));
            }
        }

    const int sub = wv >> 1;            // which 64-row image
    const int rg2 = (wv & 1) * 2;       // rowgrp base within image

    f16x8 az[3][4];
    auto loada = [&](int t_, int kt_, int s_) {
        const char* img = (kt_ < 4)
            ? (const char*)g_Xs + (size_t)((t_*16 + grp*2 + sub)*4 + kt_)*8192
            : (const char*)g_Hh + (size_t)((t_*16 + grp*2 + sub)*8 + (kt_-4))*8192;
        const char* fb = img + (size_t)(rg2*2)*1024 + lane*16;
        az[s_][0] = *(const f16x8*)(fb);
        az[s_][1] = *(const f16x8*)(fb + 1024);
        az[s_][2] = *(const f16x8*)(fb + 2048);
        az[s_][3] = *(const f16x8*)(fb + 3072);
    };

    auto wave_wait = [&](unsigned int target) {
        for (;;) {
            unsigned int v = __hip_atomic_load(&g_flags[grp][lane & 31].v,
                               __ATOMIC_RELAXED, __HIP_MEMORY_SCOPE_AGENT);
            if (__all(v >= target)) break;
            __builtin_amdgcn_s_sleep(1);
        }
        asm volatile("" ::: "memory");
    };

    // prologue: X(0) kt0..2
    loada(0, 0, 0); loada(0, 1, 1); loada(0, 2, 2);

    #pragma unroll 1
    for (int t = 0; t < 127; ++t) {
        f32x4 acc[2][4];
        #pragma unroll
        for (int m = 0; m < 2; ++m)
            #pragma unroll
            for (int n = 0; n < 4; ++n) acc[m][n] = (f32x4){0.f,0.f,0.f,0.f};

        #pragma unroll
        for (int kt = 0; kt < 12; ++kt) {
            const int s = kt % 3;
            #pragma unroll
            for (int kkl = 0; kkl < 2; ++kkl) {
                f16x8 b[4];
                if (kt < 6) {
                    #pragma unroll
                    for (int n = 0; n < 4; ++n) b[n] = bw[kt][kkl][n];
                } else {
                    const char* Br = Bb + kt*8192;
                    const int kb = kkl*64 + klo;
                    #pragma unroll
                    for (int n = 0; n < 4; ++n) {
                        int r = n*16 + l15;
                        b[n] = *(const f16x8*)(Br + r*128 + (kb ^ ((r & 7) << 4)));
                    }
                }
                #pragma unroll
                for (int n = 0; n < 4; ++n) {
                    acc[0][n] = __builtin_amdgcn_mfma_f32_16x16x32_f16(
                        az[s][0 + kkl], b[n], acc[0][n], 0, 0, 0);
                    acc[1][n] = __builtin_amdgcn_mfma_f32_16x16x32_f16(
                        az[s][2 + kkl], b[n], acc[1][n], 0, 0, 0);
                }
            }
            if (kt == 1) wave_wait((unsigned)t);   // h(t) visible before kt4 issue
            if (kt < 9) loada(t, kt + 3, s);
            else        loada(t + 1, kt - 9, s);   // X(t+1); g_Xs padded
        }

        // ---- shuffle-free epilogue: all 4 gates in-lane per cell ----
        #pragma unroll
        for (int m = 0; m < 2; ++m)
            #pragma unroll
            for (int i = 0; i < 4; ++i) {
                float iv = fsigm(acc[m][0][i] + bsv[0]);
                float fv = fsigm(acc[m][1][i] + bsv[1]);
                float gg = ftanh(acc[m][2][i] + bsv[2]);
                float ov = fsigm(acc[m][3][i] + bsv[3]);
                float cv = fv * creg[m][i] + iv * gg;
                creg[m][i] = cv;
                float hv = ov * ftanh(cv);
                int rowl = m*16 + quad*4 + i;       // 0..31 wave-local
                HsW[rowl*16 + l15] = (f16)hv;       // col = l15
            }
        asm volatile("s_waitcnt lgkmcnt(0)" ::: "memory");  // wave's Hs done
        // wave-private coalesced h store in FRAGMENT ORDER (unchanged r17)
        {
            int rg = lane >> 5, lo = lane & 31;
            int ktimg = nt >> 2;
            int kgrp  = (nt & 3) >> 1;
            int c0    = (nt & 1) * 2;
            char* img = (char*)g_Hh
                + (size_t)(((t + 1)*16 + grp*2 + sub)*8 + ktimg)*8192;
            int frag = (rg2 + rg)*2 + kgrp;
            f16x8 hv8 = *(const f16x8*)(HsW + (rg*16 + (lo & 15))*16 + (lo >> 4)*8);
            *(f16x8*)(img + frag*1024 + (size_t)(c0*16 + lo)*16) = hv8;
        }
        asm volatile("s_waitcnt vmcnt(0)" ::: "memory");  // h complete in L2
        __syncthreads();                                  // all waves done
        if (tid == 0)
            __hip_atomic_store(&g_flags[grp][nt].v, (unsigned)(t + 1),
                               __ATOMIC_RELAXED, __HIP_MEMORY_SCOPE_AGENT);
    }
}

// ---------------------------------------------------------------------------
// mlp_all: batched 3-layer MLP for ALL tokens (r17 structure, unchanged)
// ---------------------------------------------------------------------------
__global__ __launch_bounds__(256) void mlp_all(
    const float* __restrict__ b1, const float* __restrict__ b2,
    const float* __restrict__ b3, float* __restrict__ out)
{
    __shared__ char lds[65536];
    char* Wb = lds;            // 2 x 16384
    char* Ab = lds + 32768;    // 2 x 8192 (later Z2)
    char* Z1 = lds + 49152;    // 16384
    const int tid  = threadIdx.x;
    const int lane = tid & 63;
    const int w    = tid >> 6;
    const int bi   = blockIdx.x;
    const int tok  = 1 + (bi >> 4);
    const int mt   = bi & 15;
    const char* gH = (const char*)g_Hh + (size_t)(tok*16 + mt)*8*8192;
    float* outb = out + (size_t)(mt*64)*LE + (size_t)tok*E;

    float b1v[2], b2v[2], b3v[2][2];
    #pragma unroll
    for (int n = 0; n < 2; ++n) {
        int col = w*32 + n*16 + (lane & 15);
        b1v[n] = b1[col]; b2v[n] = b2[col];
        b3v[0][n] = b3[col]; b3v[1][n] = b3[128 + col];
    }
    const int kb0_0 = ((lane >> 4) << 4);

    f32x4 acc[4][2];
    #pragma unroll
    for (int m = 0; m < 4; ++m) { acc[m][0] = (f32x4){0,0,0,0}; acc[m][1] = (f32x4){0,0,0,0}; }

    #pragma unroll
    for (int it = 0; it < 2; ++it) {
        int c = w*2 + it;
        __builtin_amdgcn_global_load_lds((gu32*)(gH + c*1024 + lane*16),
                                         (lu32*)(Ab + c*1024 + lane*16), 16, 0, 0);
    }
    #pragma unroll
    for (int it = 0; it < 4; ++it) {
        int c = w*4 + it;
        __builtin_amdgcn_global_load_lds((gu32*)((const char*)g_W1s + c*1024 + lane*16),
                                         (lu32*)(Wb + c*1024 + lane*16), 16, 0, 0);
    }
    __syncthreads();

    for (int kt = 0; kt < 8; ++kt) {
        const int cur = kt & 1;
        if (kt < 7) {
            const char* gA = gH + (size_t)(kt+1)*8192;
            const char* gW = (const char*)g_W1s + (size_t)(kt+1)*16384;
            char* dA = Ab + (cur^1)*8192;
            char* dW = Wb + (cur^1)*16384;
            #pragma unroll
            for (int it = 0; it < 2; ++it) {
                int c = w*2 + it;
                __builtin_amdgcn_global_load_lds((gu32*)(gA + c*1024 + lane*16),
                                                 (lu32*)(dA + c*1024 + lane*16), 16, 0, 0);
            }
            #pragma unroll
            for (int it = 0; it < 4; ++it) {
                int c = w*4 + it;
                __builtin_amdgcn_global_load_lds((gu32*)(gW + c*1024 + lane*16),
                                                 (lu32*)(dW + c*1024 + lane*16), 16, 0, 0);
            }
        }
        const char* Ar = Ab + cur*8192;
        const char* Br = Wb + cur*16384;
        #pragma unroll
        for (int kk = 0; kk < 2; ++kk) {
            const int kb0 = kk*64 + kb0_0;
            f16x8 a[4], b[2];
            #pragma unroll
            for (int m = 0; m < 4; ++m)
                a[m] = *(const f16x8*)(Ar + (size_t)(m*2 + kk)*1024 + lane*16);
            #pragma unroll
            for (int n = 0; n < 2; ++n) {
                int br = w*32 + n*16 + (lane & 15);
                b[n] = *(const f16x8*)(Br + br*128 + (kb0 ^ ((br & 7) << 4)));
            }
            #pragma unroll
            for (int m = 0; m < 4; ++m)
                #pragma unroll
                for (int n = 0; n < 2; ++n)
                    acc[m][n] = __builtin_amdgcn_mfma_f32_16x16x32_f16(a[m], b[n], acc[m][n], 0, 0, 0);
        }
        __syncthreads();
    }

    #pragma unroll
    for (int m = 0; m < 4; ++m)
        #pragma unroll
        for (int n = 0; n < 2; ++n)
            #pragma unroll
            for (int i = 0; i < 4; ++i) {
                int row = m*16 + ((lane >> 4) << 2) + i;
                int col = w*32 + n*16 + (lane & 15);
                float v = fmaxf(acc[m][n][i] + b1v[n], 0.0f);
                *(f16*)(Z1 + (col >> 6)*8192 + row*128
                        + (((col & 63)*2) ^ ((row & 7) << 4))) = (f16)v;
            }
    __syncthreads();

    #pragma unroll
    for (int it = 0; it < 8; ++it) {
        int c = w*8 + it;
        __builtin_amdgcn_global_load_lds((gu32*)((const char*)g_W2s + c*1024 + lane*16),
                                         (lu32*)(Wb + c*1024 + lane*16), 16, 0, 0);
    }
    __syncthreads();
    #pragma unroll
    for (int m = 0; m < 4; ++m) { acc[m][0] = (f32x4){0,0,0,0}; acc[m][1] = (f32x4){0,0,0,0}; }
    #pragma unroll
    for (int kt = 0; kt < 2; ++kt)
        #pragma unroll
        for (int kk = 0; kk < 2; ++kk) {
            const int kb0 = kk*64 + kb0_0;
            f16x8 a[4], b[2];
            #pragma unroll
            for (int m = 0; m < 4; ++m) {
                int ar = m*16 + (lane & 15);
                a[m] = *(const f16x8*)(Z1 + kt*8192 + ar*128 + (kb0 ^ ((ar & 7) << 4)));
            }
            #pragma unroll
            for (int n = 0; n < 2; ++n) {
                int br = w*32 + n*16 + (lane & 15);
                b[n] = *(const f16x8*)(Wb + kt*16384 + br*128 + (kb0 ^ ((br & 7) << 4)));
            }
            #pragma unroll
            for (int m = 0; m < 4; ++m)
                #pragma unroll
                for (int n = 0; n < 2; ++n)
                    acc[m][n] = __builtin_amdgcn_mfma_f32_16x16x32_f16(a[m], b[n], acc[m][n], 0, 0, 0);
        }
    __syncthreads();

    #pragma unroll
    for (int m = 0; m < 4; ++m)
        #pragma unroll
        for (int n = 0; n < 2; ++n)
            #pragma unroll
            for (int i = 0; i < 4; ++i) {
                int row = m*16 + ((lane >> 4) << 2) + i;
                int col = w*32 + n*16 + (lane & 15);
                float v = fmaxf(acc[m][n][i] + b2v[n], 0.0f);
                *(f16*)(Ab + (col >> 6)*8192 + row*128
                        + (((col & 63)*2) ^ ((row & 7) << 4))) = (f16)v;
            }
    __syncthreads();

    #pragma unroll
    for (int nh = 0; nh < 2; ++nh) {
        #pragma unroll
        for (int it = 0; it < 8; ++it) {
            int c = w*8 + it;
            __builtin_amdgcn_global_load_lds(
                (gu32*)((const char*)g_W3s + (size_t)nh*32768 + c*1024 + lane*16),
                (lu32*)(Wb + c*1024 + lane*16), 16, 0, 0);
        }
        __syncthreads();
        #pragma unroll
        for (int m = 0; m < 4; ++m) { acc[m][0] = (f32x4){0,0,0,0}; acc[m][1] = (f32x4){0,0,0,0}; }
        #pragma unroll
        for (int kt = 0; kt < 2; ++kt)
            #pragma unroll
            for (int kk = 0; kk < 2; ++kk) {
                const int kb0 = kk*64 + kb0_0;
                f16x8 a[4], b[2];
                #pragma unroll
                for (int m = 0; m < 4; ++m) {
                    int ar = m*16 + (lane & 15);
                    a[m] = *(const f16x8*)(Ab + kt*8192 + ar*128 + (kb0 ^ ((ar & 7) << 4)));
                }
                #pragma unroll
                for (int n = 0; n < 2; ++n) {
                    int br = w*32 + n*16 + (lane & 15);
                    b[n] = *(const f16x8*)(Wb + kt*16384 + br*128 + (kb0 ^ ((br & 7) << 4)));
                }
                #pragma unroll
                for (int m = 0; m < 4; ++m)
                    #pragma unroll
                    for (int n = 0; n < 2; ++n)
                        acc[m][n] = __builtin_amdgcn_mfma_f32_16x16x32_f16(a[m], b[n], acc[m][n], 0, 0, 0);
            }
        #pragma unroll
        for (int m = 0; m < 4; ++m)
            #pragma unroll
            for (int n = 0; n < 2; ++n)
                #pragma unroll
                for (int i = 0; i < 4; ++i) {
                    int row = m*16 + ((lane >> 4) << 2) + i;
                    int col = nh*128 + w*32 + n*16 + (lane & 15);
                    outb[(size_t)row*LE + col] = acc[m][n][i] + b3v[nh][n];
                }
        __syncthreads();
    }
}

// ---------------------------------------------------------------------------
extern "C" void kernel_launch(void* const* d_in, const int* in_sizes, int n_in,
                              void* d_out, int out_size, void* d_ws, size_t ws_size,
                              hipStream_t stream) {
    (void)in_sizes; (void)n_in; (void)out_size; (void)d_ws; (void)ws_size;
    const float* hidden = (const float*)d_in[0];
    const float* padded = (const float*)d_in[1];
    const float* W_ih   = (const float*)d_in[2];
    const float* W_hh   = (const float*)d_in[3];
    const float* b_ih   = (const float*)d_in[4];
    const float* b_hh   = (const float*)d_in[5];
    const float* W1     = (const float*)d_in[6];
    const float* b1     = (const float*)d_in[7];
    const float* W2     = (const float*)d_in[8];
    const float* b2     = (const float*)d_in[9];
    const float* W3     = (const float*)d_in[10];
    const float* b3     = (const float*)d_in[11];
    float* out = (float*)d_out;

    conv_w<<<768, 256, 0, stream>>>(W_ih, W_hh, b_ih, b_hh);
    conv_mlp<<<56, 256, 0, stream>>>(W1, W2, W3);
    conv_x<<<16256, 256, 0, stream>>>(padded);
    init_kernel<<<2048, 256, 0, stream>>>(hidden, out);
    step_all<<<256, 256, 0, stream>>>();
    mlp_all<<<2032, 256, 0, stream>>>(b1, b2, b3, out);
}